// Round 16
// baseline (253.335 us; speedup 1.0000x reference)
//
#include <hip/hip_runtime.h>
#include <hip/hip_fp16.h>
#include <hip/hip_fp8.h>

#define NN 100000     // num nodes
#define DD 128        // embedding dim
#define NSUB 128      // node-range sub-slices for CSR build
#define SUBN 782      // nodes per sub-slice (128*782 = 100096 >= NN)
#define PCAP_REC 14000 // part records per sub (mean 12512, sigma ~111)
#define CSTRIDE 16000  // dense-csr ints per sub
#define PCNT_PAD 16    // one pcnt counter per 64B line
#define PEB 4096       // edges per part block
#define FP8_SCALE 64.0f
#define FP8_INV (1.0f / 64.0f)

typedef float v2f __attribute__((ext_vector_type(2)));
typedef int   v2i __attribute__((ext_vector_type(2)));
typedef int   v4i __attribute__((ext_vector_type(4)));
typedef float v4f __attribute__((ext_vector_type(4)));

#if __has_builtin(__builtin_amdgcn_cvt_pk_f32_fp8) && __has_builtin(__builtin_amdgcn_cvt_pk_fp8_f32)
#define HW_FP8 1
#else
#define HW_FP8 0
#endif

__device__ __forceinline__ v2f dec2(int w, int hi) {
#if HW_FP8
    return hi ? __builtin_amdgcn_cvt_pk_f32_fp8(w, 1)
              : __builtin_amdgcn_cvt_pk_f32_fp8(w, 0);
#else
    unsigned short hw = hi ? (unsigned short)((unsigned)w >> 16) : (unsigned short)(w & 0xffff);
    __half2_raw r = __hip_cvt_fp8x2_to_halfraw2((__hip_fp8x2_storage_t)hw, __HIP_E4M3);
    __half2 h; *reinterpret_cast<__half2_raw*>(&h) = r;
    float2 f = __half22float2(h);
    v2f o; o.x = f.x; o.y = f.y; return o;
#endif
}
__device__ __forceinline__ int enc2(float a, float b, int old, int hi) {
#if HW_FP8
    return hi ? __builtin_amdgcn_cvt_pk_fp8_f32(a, b, old, 1)
              : __builtin_amdgcn_cvt_pk_fp8_f32(a, b, old, 0);
#else
    unsigned short p = __hip_cvt_float2_to_fp8x2(make_float2(a, b), __HIP_SATFINITE, __HIP_E4M3);
    return hi ? ((old & 0xffff) | ((int)p << 16)) : ((old & ~0xffff) | (int)p);
#endif
}

// ---------------- phase 1: partition edges by node-range ----------------
__global__ __launch_bounds__(256) void part_kernel(
    const int* __restrict__ row, const int* __restrict__ col,
    int* __restrict__ pcnt, int* __restrict__ part, int E) {
    __shared__ int bcnt[NSUB], gbase[NSUB];
    if (threadIdx.x < NSUB) bcnt[threadIdx.x] = 0;
    __syncthreads();
    int beg = blockIdx.x * PEB;
    int subv[16], pv[16], recv[16];
    #pragma unroll
    for (int e = 0; e < 16; ++e) {
        int i = beg + e * 256 + (int)threadIdx.x;   // coalesced
        subv[e] = -1;
        if (i < E) {
            int c = col[i];
            int r = row[i];
            int sb = (int)((unsigned)c / SUBN);
            subv[e] = sb;
            recv[e] = (r << 10) | (c - sb * SUBN);
            pv[e] = atomicAdd(&bcnt[sb], 1);        // LDS atomic
        }
    }
    __syncthreads();
    if (threadIdx.x < NSUB)
        gbase[threadIdx.x] = atomicAdd(&pcnt[threadIdx.x * PCNT_PAD], bcnt[threadIdx.x]);
    __syncthreads();
    #pragma unroll
    for (int e = 0; e < 16; ++e) {
        if (subv[e] >= 0) {
            int p = gbase[subv[e]] + pv[e];
            if (p < PCAP_REC)
                part[(size_t)subv[e] * PCAP_REC + p] = recv[e];
        }
    }
}

// ---------------- phase 2: dense CSR build (histogram + scan + place) ----------------
__global__ __launch_bounds__(1024) void build_kernel(
    const int* __restrict__ pcnt, const int* __restrict__ part,
    int* __restrict__ cnt, int* __restrict__ offs, int* __restrict__ csr) {
    __shared__ int lcnt[SUBN];
    __shared__ int lofs[SUBN];
    __shared__ int lpos[SUBN];
    __shared__ int sh[1024];
    int s = blockIdx.x;
    int base_node = s * SUBN;
    int tid = threadIdx.x;
    for (int t = tid; t < SUBN; t += 1024) { lcnt[t] = 0; lpos[t] = 0; }
    __syncthreads();
    int M = min(pcnt[s * PCNT_PAD], PCAP_REC);
    const int* __restrict__ p = part + (size_t)s * PCAP_REC;
    for (int t = tid; t < M; t += 1024)
        atomicAdd(&lcnt[p[t] & 1023], 1);
    __syncthreads();
    int v = (tid < SUBN) ? ((lcnt[tid] + 3) & ~3) : 0;   // 4-padded size
    sh[tid] = v;
    __syncthreads();
    for (int d = 1; d < 1024; d <<= 1) {
        int add = (tid >= d) ? sh[tid - d] : 0;
        __syncthreads();
        sh[tid] += add;
        __syncthreads();
    }
    if (tid < SUBN) {
        int excl = sh[tid] - v;
        lofs[tid] = excl;
        int node = base_node + tid;
        if (node < NN) {
            offs[node] = s * CSTRIDE + excl;
            cnt[node] = lcnt[tid];
        }
    }
    __syncthreads();
    int* __restrict__ dst = csr + (size_t)s * CSTRIDE;
    for (int t = tid; t < M; t += 1024) {
        int rec = p[t];
        int local = rec & 1023;
        int pos = lofs[local] + atomicAdd(&lpos[local], 1);
        if (pos < CSTRIDE) dst[pos] = rec >> 10;
    }
}

// ---- conv: x0'_8 = fp8(64*rsqrt(deg)*emb);  embq = 0.25*emb (fp16) ----
__global__ void conv_kernel(const float* __restrict__ emb, const int* __restrict__ cnt,
                            unsigned int* __restrict__ x0_8, __half* __restrict__ embq) {
    int i = blockIdx.x * blockDim.x + threadIdx.x;   // one thread per 4 floats
    if (i < NN * DD / 4) {
        int n = cnt[i >> 5];                         // (i*4)/128
        float s = n > 0 ? FP8_SCALE * rsqrtf((float)n) : 0.0f;
        float4 v = ((const float4*)emb)[i];
        int w = enc2(s * v.x, s * v.y, 0, 0);
        w = enc2(s * v.z, s * v.w, w, 1);
        x0_8[i] = (unsigned)w;
        __half2 q[2];
        q[0] = __float22half2_rn(make_float2(0.25f * v.x, 0.25f * v.y));
        q[1] = __float22half2_rn(make_float2(0.25f * v.z, 0.25f * v.w));
        __builtin_nontemporal_store(*(v2i*)q, (v2i*)(embq + (size_t)i * 4));
    }
}

// ---------------- propagation layer ----------------
// One wave per node; 8 groups x 8 lanes; group g -> edges g, g+8, ...;
// lane q loads int4 (16 fp8) covering dims [16q,16q+16) -> 8 edge-loads in
// flight per wave (2x the MLP of the 4-group layout), half the load instrs.
// Window csr[off+lane] preloaded predicated; src via __shfl.
// HW fp8->f32 decode, packed f32 accumulate, 3-stage cross-group reduce.
// MODE 0: x16_out = a/(64n) (= x'_k);  x8_out = fp8(a/n) (= 64*x'_k)
// MODE 1: out = embq + 0.25*((u1+u2)*sqrt(n) + (rsqrt(n)/64)*a)
template<int MODE>
__global__ __launch_bounds__(256) void gather_kernel(
    const unsigned char* __restrict__ x8,
    const int* __restrict__ cnt,
    const int* __restrict__ offs,
    const int* __restrict__ csr,
    __half* __restrict__ x16_out,
    unsigned char* __restrict__ x8_out,
    const __half* __restrict__ embq,
    const __half* __restrict__ u1p,
    const __half* __restrict__ u2p,
    float* __restrict__ out)
{
    int node = __builtin_amdgcn_readfirstlane(blockIdx.x * 4 + (threadIdx.x >> 6));
    if (node >= NN) return;
    int lane = threadIdx.x & 63;
    int g = lane >> 3;        // edge group 0..7
    int q = lane & 7;         // dim block: dims [16q, 16q+16)

    int n = cnt[node];
    int off = offs[node];                          // 4-aligned int index
    int srcs = (lane < n) ? csr[off + lane] : 0;   // predicated window preload

    v2f a[8];
    #pragma unroll
    for (int k = 0; k < 8; ++k) { a[k].x = 0.f; a[k].y = 0.f; }

    int nn = n < 64 ? n : 64;
    int T = (nn + 7) >> 3;                      // uniform trip count
    for (int t = 0; t < T; ++t) {
        int j = (t << 3) | g;
        int s = __shfl(srcs, j);
        if (j < nn) {
            int4 raw = *(const int4*)(x8 + ((size_t)s << 7) + (q << 4));  // 16B
            a[0] += dec2(raw.x, 0); a[1] += dec2(raw.x, 1);
            a[2] += dec2(raw.y, 0); a[3] += dec2(raw.y, 1);
            a[4] += dec2(raw.z, 0); a[5] += dec2(raw.z, 1);
            a[6] += dec2(raw.w, 0); a[7] += dec2(raw.w, 1);
        }
    }
    for (int j = 64 + g; j < n; j += 8) {       // P(deg>64) ~ 1e-20
        int s = csr[off + j];
        int4 raw = *(const int4*)(x8 + ((size_t)s << 7) + (q << 4));
        a[0] += dec2(raw.x, 0); a[1] += dec2(raw.x, 1);
        a[2] += dec2(raw.y, 0); a[3] += dec2(raw.y, 1);
        a[4] += dec2(raw.z, 0); a[5] += dec2(raw.z, 1);
        a[6] += dec2(raw.w, 0); a[7] += dec2(raw.w, 1);
    }
    // cross-group reduce (lanes +-8, +-16, +-32)
    float av[16];
    #pragma unroll
    for (int k = 0; k < 8; ++k) { av[2 * k] = a[k].x; av[2 * k + 1] = a[k].y; }
    #pragma unroll
    for (int k = 0; k < 16; ++k) {
        av[k] += __shfl_xor(av[k], 8);
        av[k] += __shfl_xor(av[k], 16);
        av[k] += __shfl_xor(av[k], 32);
    }

    if (g == 0) {               // 8 lanes, lane q owns dims [16q, 16q+16)
        float fn = (float)n;
        if (MODE == 0) {
            float inv = n > 0 ? 1.0f / fn : 0.0f;
            float m16 = inv * FP8_INV;                       // -> x'_k
            __half2 h16[8];
            #pragma unroll
            for (int k = 0; k < 8; ++k)
                h16[k] = __float22half2_rn(make_float2(av[2 * k] * m16, av[2 * k + 1] * m16));
            __half* d16 = x16_out + (size_t)node * DD + q * 16;
            __builtin_nontemporal_store(*(v4i*)&h16[0], (v4i*)d16);
            __builtin_nontemporal_store(*(v4i*)&h16[4], (v4i*)(d16 + 8));
            v4i w8;
            int w = enc2(av[0] * inv, av[1] * inv, 0, 0);
            w8.x = enc2(av[2] * inv, av[3] * inv, w, 1);
            w = enc2(av[4] * inv, av[5] * inv, 0, 0);
            w8.y = enc2(av[6] * inv, av[7] * inv, w, 1);
            w = enc2(av[8] * inv, av[9] * inv, 0, 0);
            w8.z = enc2(av[10] * inv, av[11] * inv, w, 1);
            w = enc2(av[12] * inv, av[13] * inv, 0, 0);
            w8.w = enc2(av[14] * inv, av[15] * inv, w, 1);
            __builtin_nontemporal_store(w8, (v4i*)(x8_out + ((size_t)node << 7) + (q << 4)));
        } else {
            float rr4 = n > 0 ? 0.25f * sqrtf(fn) : 0.0f;
            float d644 = n > 0 ? 0.25f * FP8_INV * rsqrtf(fn) : 0.0f;
            size_t eo = (size_t)node * DD + q * 16;
            int4 bq0 = *(const int4*)(embq + eo);
            int4 bq1 = *(const int4*)(embq + eo + 8);
            int4 b10 = *(const int4*)(u1p + eo);
            int4 b11 = *(const int4*)(u1p + eo + 8);
            int4 b20 = *(const int4*)(u2p + eo);
            int4 b21 = *(const int4*)(u2p + eo + 8);
            const __half2* hq0 = (const __half2*)&bq0;
            const __half2* hq1 = (const __half2*)&bq1;
            const __half2* h10 = (const __half2*)&b10;
            const __half2* h11 = (const __half2*)&b11;
            const __half2* h20 = (const __half2*)&b20;
            const __half2* h21 = (const __half2*)&b21;
            float o16[16];
            #pragma unroll
            for (int k = 0; k < 4; ++k) {
                float2 eq = __half22float2(hq0[k]);
                float2 uu1 = __half22float2(h10[k]);
                float2 uu2 = __half22float2(h20[k]);
                o16[2 * k]     = eq.x + (uu1.x + uu2.x) * rr4 + d644 * av[2 * k];
                o16[2 * k + 1] = eq.y + (uu1.y + uu2.y) * rr4 + d644 * av[2 * k + 1];
            }
            #pragma unroll
            for (int k = 0; k < 4; ++k) {
                float2 eq = __half22float2(hq1[k]);
                float2 uu1 = __half22float2(h11[k]);
                float2 uu2 = __half22float2(h21[k]);
                o16[8 + 2 * k]     = eq.x + (uu1.x + uu2.x) * rr4 + d644 * av[8 + 2 * k];
                o16[8 + 2 * k + 1] = eq.y + (uu1.y + uu2.y) * rr4 + d644 * av[8 + 2 * k + 1];
            }
            float* dst = out + eo;
            #pragma unroll
            for (int k = 0; k < 4; ++k) {
                v4f vv; vv.x = o16[4 * k]; vv.y = o16[4 * k + 1];
                vv.z = o16[4 * k + 2]; vv.w = o16[4 * k + 3];
                __builtin_nontemporal_store(vv, (v4f*)(dst + 4 * k));
            }
        }
    }
}

// ---------------- launch ----------------

extern "C" void kernel_launch(void* const* d_in, const int* in_sizes, int n_in,
                              void* d_out, int out_size, void* d_ws, size_t ws_size,
                              hipStream_t stream) {
    const float* emb = (const float*)d_in[0];
    const int* ei = (const int*)d_in[1];
    const int E = in_sizes[1] / 2;
    const int* row = ei;        // edge_index[0]
    const int* col = ei + E;    // edge_index[1]
    float* out = (float*)d_out;

    char* w = (char*)d_ws;
    auto align_up = [](size_t v) { return (v + 255) & ~(size_t)255; };
    size_t o = 0;
    int* pcnt = (int*)(w + o);           o = align_up(o + (size_t)NSUB * PCNT_PAD * 4);
    int* cnt  = (int*)(w + o);           o = align_up(o + (size_t)NN * 4);
    int* offs = (int*)(w + o);           o = align_up(o + (size_t)NN * 4);
    int* csr  = (int*)(w + o);           o = align_up(o + (size_t)NSUB * CSTRIDE * 4); // 8.2 MB
    // union: part (7.2 MB, dead after build) shares with xs2_8 (12.8 MB, born in g2)
    char* upx = w + o;                   o = align_up(o + (size_t)NN * DD);            // 12.8 MB
    int* part = (int*)upx;
    unsigned char* xs2_8 = (unsigned char*)upx;
    unsigned char* xs0_8 = (unsigned char*)(w + o); o = align_up(o + (size_t)NN * DD); // 12.8 MB
    unsigned char* xs1_8 = (unsigned char*)(w + o); o = align_up(o + (size_t)NN * DD); // 12.8 MB
    __half* xs1_16 = (__half*)(w + o);   o = align_up(o + (size_t)NN * DD * 2);        // 25.6 MB
    __half* xs2_16 = (__half*)(w + o);   o = align_up(o + (size_t)NN * DD * 2);        // 25.6 MB
    __half* embq   = (__half*)(w + o);   o = align_up(o + (size_t)NN * DD * 2);        // 25.6 MB

    hipMemsetAsync(pcnt, 0, (size_t)NSUB * PCNT_PAD * 4, stream);

    part_kernel<<<(E + PEB - 1) / PEB, 256, 0, stream>>>(row, col, pcnt, part, E);
    build_kernel<<<NSUB, 1024, 0, stream>>>(pcnt, part, cnt, offs, csr);
    conv_kernel<<<(NN * DD / 4 + 255) / 256, 256, 0, stream>>>(emb, cnt, (unsigned int*)xs0_8, embq);

    const int lb = (NN * 64) / 256;  // 25000 blocks, 1 wave per node
    gather_kernel<0><<<lb, 256, 0, stream>>>(xs0_8, cnt, offs, csr, xs1_16, xs1_8,
                                             nullptr, nullptr, nullptr, nullptr);
    gather_kernel<0><<<lb, 256, 0, stream>>>(xs1_8, cnt, offs, csr, xs2_16, xs2_8,
                                             nullptr, nullptr, nullptr, nullptr);
    gather_kernel<1><<<lb, 256, 0, stream>>>(xs2_8, cnt, offs, csr, nullptr, nullptr,
                                             embq, xs1_16, xs2_16, out);
}

// Round 17
// 198.238 us; speedup vs baseline: 1.2779x; 1.2779x over previous
//
#include <hip/hip_runtime.h>
#include <hip/hip_fp16.h>
#include <hip/hip_fp8.h>

#define NN 100000     // num nodes
#define DD 128        // embedding dim
#define NSUB 128      // node-range sub-slices for CSR build
#define SUBN 782      // nodes per sub-slice (128*782 = 100096 >= NN)
#define PCAP_REC 14000 // part records per sub (mean 12512, sigma ~111)
#define CSTRIDE 16000  // dense-csr ints per sub
#define PCNT_PAD 16    // one pcnt counter per 64B line
#define PEB 4096       // edges per part block
#define FP8_SCALE 64.0f
#define FP8_INV (1.0f / 64.0f)

typedef float v2f __attribute__((ext_vector_type(2)));
typedef int   v2i __attribute__((ext_vector_type(2)));
typedef int   v4i __attribute__((ext_vector_type(4)));
typedef float v4f __attribute__((ext_vector_type(4)));

#if __has_builtin(__builtin_amdgcn_cvt_pk_f32_fp8) && __has_builtin(__builtin_amdgcn_cvt_pk_fp8_f32)
#define HW_FP8 1
#else
#define HW_FP8 0
#endif

__device__ __forceinline__ v2f dec2(int w, int hi) {
#if HW_FP8
    return hi ? __builtin_amdgcn_cvt_pk_f32_fp8(w, 1)
              : __builtin_amdgcn_cvt_pk_f32_fp8(w, 0);
#else
    unsigned short hw = hi ? (unsigned short)((unsigned)w >> 16) : (unsigned short)(w & 0xffff);
    __half2_raw r = __hip_cvt_fp8x2_to_halfraw2((__hip_fp8x2_storage_t)hw, __HIP_E4M3);
    __half2 h; *reinterpret_cast<__half2_raw*>(&h) = r;
    float2 f = __half22float2(h);
    v2f o; o.x = f.x; o.y = f.y; return o;
#endif
}
__device__ __forceinline__ int enc2(float a, float b, int old, int hi) {
#if HW_FP8
    return hi ? __builtin_amdgcn_cvt_pk_fp8_f32(a, b, old, 1)
              : __builtin_amdgcn_cvt_pk_fp8_f32(a, b, old, 0);
#else
    unsigned short p = __hip_cvt_float2_to_fp8x2(make_float2(a, b), __HIP_SATFINITE, __HIP_E4M3);
    return hi ? ((old & 0xffff) | ((int)p << 16)) : ((old & ~0xffff) | (int)p);
#endif
}

// ---------------- phase 1: partition edges by node-range ----------------
__global__ __launch_bounds__(256) void part_kernel(
    const int* __restrict__ row, const int* __restrict__ col,
    int* __restrict__ pcnt, int* __restrict__ part, int E) {
    __shared__ int bcnt[NSUB], gbase[NSUB];
    if (threadIdx.x < NSUB) bcnt[threadIdx.x] = 0;
    __syncthreads();
    int beg = blockIdx.x * PEB;
    int subv[16], pv[16], recv[16];
    #pragma unroll
    for (int e = 0; e < 16; ++e) {
        int i = beg + e * 256 + (int)threadIdx.x;   // coalesced
        subv[e] = -1;
        if (i < E) {
            int c = col[i];
            int r = row[i];
            int sb = (int)((unsigned)c / SUBN);
            subv[e] = sb;
            recv[e] = (r << 10) | (c - sb * SUBN);
            pv[e] = atomicAdd(&bcnt[sb], 1);        // LDS atomic
        }
    }
    __syncthreads();
    if (threadIdx.x < NSUB)
        gbase[threadIdx.x] = atomicAdd(&pcnt[threadIdx.x * PCNT_PAD], bcnt[threadIdx.x]);
    __syncthreads();
    #pragma unroll
    for (int e = 0; e < 16; ++e) {
        if (subv[e] >= 0) {
            int p = gbase[subv[e]] + pv[e];
            if (p < PCAP_REC)
                part[(size_t)subv[e] * PCAP_REC + p] = recv[e];
        }
    }
}

// ---------------- phase 2: dense CSR build (histogram + scan + place) ----------------
__global__ __launch_bounds__(1024) void build_kernel(
    const int* __restrict__ pcnt, const int* __restrict__ part,
    int* __restrict__ cnt, int* __restrict__ offs, int* __restrict__ csr) {
    __shared__ int lcnt[SUBN];
    __shared__ int lofs[SUBN];
    __shared__ int lpos[SUBN];
    __shared__ int sh[1024];
    int s = blockIdx.x;
    int base_node = s * SUBN;
    int tid = threadIdx.x;
    for (int t = tid; t < SUBN; t += 1024) { lcnt[t] = 0; lpos[t] = 0; }
    __syncthreads();
    int M = min(pcnt[s * PCNT_PAD], PCAP_REC);
    const int* __restrict__ p = part + (size_t)s * PCAP_REC;
    for (int t = tid; t < M; t += 1024)
        atomicAdd(&lcnt[p[t] & 1023], 1);
    __syncthreads();
    int v = (tid < SUBN) ? ((lcnt[tid] + 3) & ~3) : 0;   // 4-padded size
    sh[tid] = v;
    __syncthreads();
    for (int d = 1; d < 1024; d <<= 1) {
        int add = (tid >= d) ? sh[tid - d] : 0;
        __syncthreads();
        sh[tid] += add;
        __syncthreads();
    }
    if (tid < SUBN) {
        int excl = sh[tid] - v;
        lofs[tid] = excl;
        int node = base_node + tid;
        if (node < NN) {
            offs[node] = s * CSTRIDE + excl;
            cnt[node] = lcnt[tid];
        }
    }
    __syncthreads();
    int* __restrict__ dst = csr + (size_t)s * CSTRIDE;
    for (int t = tid; t < M; t += 1024) {
        int rec = p[t];
        int local = rec & 1023;
        int pos = lofs[local] + atomicAdd(&lpos[local], 1);
        if (pos < CSTRIDE) dst[pos] = rec >> 10;
    }
}

// ---- conv: x0'_8 = fp8(64*rsqrt(deg)*emb);  embq = 0.25*emb (fp16) ----
__global__ void conv_kernel(const float* __restrict__ emb, const int* __restrict__ cnt,
                            unsigned int* __restrict__ x0_8, __half* __restrict__ embq) {
    int i = blockIdx.x * blockDim.x + threadIdx.x;   // one thread per 4 floats
    if (i < NN * DD / 4) {
        int n = cnt[i >> 5];                         // (i*4)/128
        float s = n > 0 ? FP8_SCALE * rsqrtf((float)n) : 0.0f;
        float4 v = ((const float4*)emb)[i];
        int w = enc2(s * v.x, s * v.y, 0, 0);
        w = enc2(s * v.z, s * v.w, w, 1);
        x0_8[i] = (unsigned)w;
        __half2 q[2];
        q[0] = __float22half2_rn(make_float2(0.25f * v.x, 0.25f * v.y));
        q[1] = __float22half2_rn(make_float2(0.25f * v.z, 0.25f * v.w));
        __builtin_nontemporal_store(*(v2i*)q, (v2i*)(embq + (size_t)i * 4));
    }
}

// ---------------- propagation layer ----------------
// One wave per node; 4 groups x 16 lanes (R15 structure, VGPR~20, occ~74%);
// edge loop unrolled x2 with both loads issued before either decode ->
// doubles outstanding 64B-line requests per wave (Little's-law limited).
// MODE 0: x16_out = a/(64n) (= x'_k);  x8_out = fp8(a/n) (= 64*x'_k)
// MODE 1: out = embq + 0.25*((u1+u2)*sqrt(n) + (rsqrt(n)/64)*a)
template<int MODE>
__global__ __launch_bounds__(256) void gather_kernel(
    const unsigned char* __restrict__ x8,
    const int* __restrict__ cnt,
    const int* __restrict__ offs,
    const int* __restrict__ csr,
    __half* __restrict__ x16_out,
    unsigned char* __restrict__ x8_out,
    const __half* __restrict__ embq,
    const __half* __restrict__ u1p,
    const __half* __restrict__ u2p,
    float* __restrict__ out)
{
    int node = __builtin_amdgcn_readfirstlane(blockIdx.x * 4 + (threadIdx.x >> 6));
    if (node >= NN) return;
    int lane = threadIdx.x & 63;
    int g = lane >> 4;        // edge group 0..3
    int q = lane & 15;        // dim block: dims [8q, 8q+8)

    int n = cnt[node];
    int off = offs[node];                          // 4-aligned int index
    int srcs = (lane < n) ? csr[off + lane] : 0;   // predicated window preload

    v2f a0 = {0.f, 0.f}, a1 = {0.f, 0.f}, a2 = {0.f, 0.f}, a3 = {0.f, 0.f};

    int nn = n < 64 ? n : 64;
    // main loop: 2 iterations at once, both loads in flight before decode
    int t = 0;
    for (; 4 * t + 8 <= nn; t += 2) {
        int j0 = (t << 2) | g;                     // < nn for all groups
        int j1 = j0 + 4;                           // < nn for all groups
        int s0 = __shfl(srcs, j0);
        int s1 = __shfl(srcs, j1);
        int2 r0 = *(const int2*)(x8 + ((size_t)s0 << 7) + (q << 3));
        int2 r1 = *(const int2*)(x8 + ((size_t)s1 << 7) + (q << 3));
        a0 += dec2(r0.x, 0); a1 += dec2(r0.x, 1);
        a2 += dec2(r0.y, 0); a3 += dec2(r0.y, 1);
        a0 += dec2(r1.x, 0); a1 += dec2(r1.x, 1);
        a2 += dec2(r1.y, 0); a3 += dec2(r1.y, 1);
    }
    int T = (nn + 3) >> 2;
    for (; t < T; ++t) {                           // predicated tail
        int j = (t << 2) | g;
        int s = __shfl(srcs, j);
        if (j < nn) {
            int2 raw = *(const int2*)(x8 + ((size_t)s << 7) + (q << 3));
            a0 += dec2(raw.x, 0); a1 += dec2(raw.x, 1);
            a2 += dec2(raw.y, 0); a3 += dec2(raw.y, 1);
        }
    }
    for (int j = 64 + g; j < n; j += 4) {          // P(deg>64) ~ 1e-20
        int s = csr[off + j];
        int2 raw = *(const int2*)(x8 + ((size_t)s << 7) + (q << 3));
        a0 += dec2(raw.x, 0); a1 += dec2(raw.x, 1);
        a2 += dec2(raw.y, 0); a3 += dec2(raw.y, 1);
    }
    // cross-group reduce (lanes +-16, +-32)
    float av[8] = {a0.x, a0.y, a1.x, a1.y, a2.x, a2.y, a3.x, a3.y};
    #pragma unroll
    for (int k = 0; k < 8; ++k) {
        av[k] += __shfl_xor(av[k], 16);
        av[k] += __shfl_xor(av[k], 32);
    }

    if (g == 0) {
        float fn = (float)n;
        if (MODE == 0) {
            float inv = n > 0 ? 1.0f / fn : 0.0f;
            float m16 = inv * FP8_INV;                       // -> x'_k
            __half2 h16[4];
            #pragma unroll
            for (int k = 0; k < 4; ++k)
                h16[k] = __float22half2_rn(make_float2(av[2 * k] * m16, av[2 * k + 1] * m16));
            __builtin_nontemporal_store(*(v4i*)h16, (v4i*)(x16_out + (size_t)node * DD + q * 8));
            int w0 = enc2(av[0] * inv, av[1] * inv, 0, 0);
            w0 = enc2(av[2] * inv, av[3] * inv, w0, 1);
            int w1 = enc2(av[4] * inv, av[5] * inv, 0, 0);
            w1 = enc2(av[6] * inv, av[7] * inv, w1, 1);
            v2i w01; w01.x = w0; w01.y = w1;
            __builtin_nontemporal_store(w01, (v2i*)(x8_out + ((size_t)node << 7) + (q << 3)));
        } else {
            float rr4 = n > 0 ? 0.25f * sqrtf(fn) : 0.0f;
            float d644 = n > 0 ? 0.25f * FP8_INV * rsqrtf(fn) : 0.0f;
            size_t eo = (size_t)node * DD + q * 8;
            int4 bq = *(const int4*)(embq + eo);
            int4 b1 = *(const int4*)(u1p + eo);
            int4 b2 = *(const int4*)(u2p + eo);
            const __half2* hq = (const __half2*)&bq;
            const __half2* h1 = (const __half2*)&b1;
            const __half2* h2v = (const __half2*)&b2;
            float o8[8];
            #pragma unroll
            for (int k = 0; k < 4; ++k) {
                float2 eq = __half22float2(hq[k]);
                float2 uu1 = __half22float2(h1[k]);
                float2 uu2 = __half22float2(h2v[k]);
                o8[2 * k]     = eq.x + (uu1.x + uu2.x) * rr4 + d644 * av[2 * k];
                o8[2 * k + 1] = eq.y + (uu1.y + uu2.y) * rr4 + d644 * av[2 * k + 1];
            }
            float* dst = out + eo;
            v4f lo; lo.x = o8[0]; lo.y = o8[1]; lo.z = o8[2]; lo.w = o8[3];
            v4f hi; hi.x = o8[4]; hi.y = o8[5]; hi.z = o8[6]; hi.w = o8[7];
            __builtin_nontemporal_store(lo, (v4f*)dst);
            __builtin_nontemporal_store(hi, (v4f*)(dst + 4));
        }
    }
}

// ---------------- launch ----------------

extern "C" void kernel_launch(void* const* d_in, const int* in_sizes, int n_in,
                              void* d_out, int out_size, void* d_ws, size_t ws_size,
                              hipStream_t stream) {
    const float* emb = (const float*)d_in[0];
    const int* ei = (const int*)d_in[1];
    const int E = in_sizes[1] / 2;
    const int* row = ei;        // edge_index[0]
    const int* col = ei + E;    // edge_index[1]
    float* out = (float*)d_out;

    char* w = (char*)d_ws;
    auto align_up = [](size_t v) { return (v + 255) & ~(size_t)255; };
    size_t o = 0;
    int* pcnt = (int*)(w + o);           o = align_up(o + (size_t)NSUB * PCNT_PAD * 4);
    int* cnt  = (int*)(w + o);           o = align_up(o + (size_t)NN * 4);
    int* offs = (int*)(w + o);           o = align_up(o + (size_t)NN * 4);
    int* csr  = (int*)(w + o);           o = align_up(o + (size_t)NSUB * CSTRIDE * 4); // 8.2 MB
    // union: part (7.2 MB, dead after build) shares with xs2_8 (12.8 MB, born in g2)
    char* upx = w + o;                   o = align_up(o + (size_t)NN * DD);            // 12.8 MB
    int* part = (int*)upx;
    unsigned char* xs2_8 = (unsigned char*)upx;
    unsigned char* xs0_8 = (unsigned char*)(w + o); o = align_up(o + (size_t)NN * DD); // 12.8 MB
    unsigned char* xs1_8 = (unsigned char*)(w + o); o = align_up(o + (size_t)NN * DD); // 12.8 MB
    __half* xs1_16 = (__half*)(w + o);   o = align_up(o + (size_t)NN * DD * 2);        // 25.6 MB
    __half* xs2_16 = (__half*)(w + o);   o = align_up(o + (size_t)NN * DD * 2);        // 25.6 MB
    __half* embq   = (__half*)(w + o);   o = align_up(o + (size_t)NN * DD * 2);        // 25.6 MB

    hipMemsetAsync(pcnt, 0, (size_t)NSUB * PCNT_PAD * 4, stream);

    part_kernel<<<(E + PEB - 1) / PEB, 256, 0, stream>>>(row, col, pcnt, part, E);
    build_kernel<<<NSUB, 1024, 0, stream>>>(pcnt, part, cnt, offs, csr);
    conv_kernel<<<(NN * DD / 4 + 255) / 256, 256, 0, stream>>>(emb, cnt, (unsigned int*)xs0_8, embq);

    const int lb = (NN * 64) / 256;  // 25000 blocks, 1 wave per node
    gather_kernel<0><<<lb, 256, 0, stream>>>(xs0_8, cnt, offs, csr, xs1_16, xs1_8,
                                             nullptr, nullptr, nullptr, nullptr);
    gather_kernel<0><<<lb, 256, 0, stream>>>(xs1_8, cnt, offs, csr, xs2_16, xs2_8,
                                             nullptr, nullptr, nullptr, nullptr);
    gather_kernel<1><<<lb, 256, 0, stream>>>(xs2_8, cnt, offs, csr, nullptr, nullptr,
                                             embq, xs1_16, xs2_16, out);
}

// Round 18
// 193.398 us; speedup vs baseline: 1.3099x; 1.0250x over previous
//
#include <hip/hip_runtime.h>
#include <hip/hip_fp16.h>
#include <hip/hip_fp8.h>

#define NN 100000     // num nodes
#define DD 128        // embedding dim
#define NSUB 128      // node-range sub-slices for CSR build
#define SUBN 782      // nodes per sub-slice (128*782 = 100096 >= NN)
#define PCAP_REC 14000 // part records per sub (mean 12512, sigma ~111)
#define CSTRIDE 16000  // dense-csr ints per sub
#define PCNT_PAD 16    // one pcnt counter per 64B line
#define PEB 4096       // edges per part block
#define FP8_SCALE 64.0f
#define FP8_INV (1.0f / 64.0f)

typedef float v2f __attribute__((ext_vector_type(2)));
typedef int   v2i __attribute__((ext_vector_type(2)));
typedef int   v4i __attribute__((ext_vector_type(4)));
typedef float v4f __attribute__((ext_vector_type(4)));

#if __has_builtin(__builtin_amdgcn_cvt_pk_f32_fp8) && __has_builtin(__builtin_amdgcn_cvt_pk_fp8_f32)
#define HW_FP8 1
#else
#define HW_FP8 0
#endif

__device__ __forceinline__ v2f dec2(int w, int hi) {
#if HW_FP8
    return hi ? __builtin_amdgcn_cvt_pk_f32_fp8(w, 1)
              : __builtin_amdgcn_cvt_pk_f32_fp8(w, 0);
#else
    unsigned short hw = hi ? (unsigned short)((unsigned)w >> 16) : (unsigned short)(w & 0xffff);
    __half2_raw r = __hip_cvt_fp8x2_to_halfraw2((__hip_fp8x2_storage_t)hw, __HIP_E4M3);
    __half2 h; *reinterpret_cast<__half2_raw*>(&h) = r;
    float2 f = __half22float2(h);
    v2f o; o.x = f.x; o.y = f.y; return o;
#endif
}
__device__ __forceinline__ int enc2(float a, float b, int old, int hi) {
#if HW_FP8
    return hi ? __builtin_amdgcn_cvt_pk_fp8_f32(a, b, old, 1)
              : __builtin_amdgcn_cvt_pk_fp8_f32(a, b, old, 0);
#else
    unsigned short p = __hip_cvt_float2_to_fp8x2(make_float2(a, b), __HIP_SATFINITE, __HIP_E4M3);
    return hi ? ((old & 0xffff) | ((int)p << 16)) : ((old & ~0xffff) | (int)p);
#endif
}

// ---------------- phase 1: partition edges by node-range ----------------
__global__ __launch_bounds__(256) void part_kernel(
    const int* __restrict__ row, const int* __restrict__ col,
    int* __restrict__ pcnt, int* __restrict__ part, int E) {
    __shared__ int bcnt[NSUB], gbase[NSUB];
    if (threadIdx.x < NSUB) bcnt[threadIdx.x] = 0;
    __syncthreads();
    int beg = blockIdx.x * PEB;
    int subv[16], pv[16], recv[16];
    #pragma unroll
    for (int e = 0; e < 16; ++e) {
        int i = beg + e * 256 + (int)threadIdx.x;   // coalesced
        subv[e] = -1;
        if (i < E) {
            int c = col[i];
            int r = row[i];
            int sb = (int)((unsigned)c / SUBN);
            subv[e] = sb;
            recv[e] = (r << 10) | (c - sb * SUBN);
            pv[e] = atomicAdd(&bcnt[sb], 1);        // LDS atomic
        }
    }
    __syncthreads();
    if (threadIdx.x < NSUB)
        gbase[threadIdx.x] = atomicAdd(&pcnt[threadIdx.x * PCNT_PAD], bcnt[threadIdx.x]);
    __syncthreads();
    #pragma unroll
    for (int e = 0; e < 16; ++e) {
        if (subv[e] >= 0) {
            int p = gbase[subv[e]] + pv[e];
            if (p < PCAP_REC)
                part[(size_t)subv[e] * PCAP_REC + p] = recv[e];
        }
    }
}

// ---------------- phase 2: dense CSR build (histogram + scan + place) ----------------
__global__ __launch_bounds__(1024) void build_kernel(
    const int* __restrict__ pcnt, const int* __restrict__ part,
    int* __restrict__ cnt, int* __restrict__ offs, int* __restrict__ csr) {
    __shared__ int lcnt[SUBN];
    __shared__ int lofs[SUBN];
    __shared__ int lpos[SUBN];
    __shared__ int sh[1024];
    int s = blockIdx.x;
    int base_node = s * SUBN;
    int tid = threadIdx.x;
    for (int t = tid; t < SUBN; t += 1024) { lcnt[t] = 0; lpos[t] = 0; }
    __syncthreads();
    int M = min(pcnt[s * PCNT_PAD], PCAP_REC);
    const int* __restrict__ p = part + (size_t)s * PCAP_REC;
    for (int t = tid; t < M; t += 1024)
        atomicAdd(&lcnt[p[t] & 1023], 1);
    __syncthreads();
    int v = (tid < SUBN) ? ((lcnt[tid] + 3) & ~3) : 0;   // 4-padded size
    sh[tid] = v;
    __syncthreads();
    for (int d = 1; d < 1024; d <<= 1) {
        int add = (tid >= d) ? sh[tid - d] : 0;
        __syncthreads();
        sh[tid] += add;
        __syncthreads();
    }
    if (tid < SUBN) {
        int excl = sh[tid] - v;
        lofs[tid] = excl;
        int node = base_node + tid;
        if (node < NN) {
            offs[node] = s * CSTRIDE + excl;
            cnt[node] = lcnt[tid];
        }
    }
    __syncthreads();
    int* __restrict__ dst = csr + (size_t)s * CSTRIDE;
    for (int t = tid; t < M; t += 1024) {
        int rec = p[t];
        int local = rec & 1023;
        int pos = lofs[local] + atomicAdd(&lpos[local], 1);
        if (pos < CSTRIDE) dst[pos] = rec >> 10;
    }
}

// ---- conv: x0'_8 = fp8(64*rsqrt(deg)*emb);  embq = 0.25*emb (fp16) ----
__global__ void conv_kernel(const float* __restrict__ emb, const int* __restrict__ cnt,
                            unsigned int* __restrict__ x0_8, __half* __restrict__ embq) {
    int i = blockIdx.x * blockDim.x + threadIdx.x;   // one thread per 4 floats
    if (i < NN * DD / 4) {
        int n = cnt[i >> 5];                         // (i*4)/128
        float s = n > 0 ? FP8_SCALE * rsqrtf((float)n) : 0.0f;
        float4 v = ((const float4*)emb)[i];
        int w = enc2(s * v.x, s * v.y, 0, 0);
        w = enc2(s * v.z, s * v.w, w, 1);
        x0_8[i] = (unsigned)w;
        __half2 q[2];
        q[0] = __float22half2_rn(make_float2(0.25f * v.x, 0.25f * v.y));
        q[1] = __float22half2_rn(make_float2(0.25f * v.z, 0.25f * v.w));
        __builtin_nontemporal_store(*(v2i*)q, (v2i*)(embq + (size_t)i * 4));
    }
}

// ---------------- propagation layer ----------------
// One wave per node; 4 groups x 16 lanes; edge loop unrolled x4 (4 line
// requests in flight before any decode), then x2, then predicated x1 tail.
// MODE 0: x16_out = a/(64n) (= x'_k);  x8_out = fp8(a/n) (= 64*x'_k)
// MODE 1: out = embq + 0.25*((u1+u2)*sqrt(n) + (rsqrt(n)/64)*a)
template<int MODE>
__global__ __launch_bounds__(256) void gather_kernel(
    const unsigned char* __restrict__ x8,
    const int* __restrict__ cnt,
    const int* __restrict__ offs,
    const int* __restrict__ csr,
    __half* __restrict__ x16_out,
    unsigned char* __restrict__ x8_out,
    const __half* __restrict__ embq,
    const __half* __restrict__ u1p,
    const __half* __restrict__ u2p,
    float* __restrict__ out)
{
    int node = __builtin_amdgcn_readfirstlane(blockIdx.x * 4 + (threadIdx.x >> 6));
    if (node >= NN) return;
    int lane = threadIdx.x & 63;
    int g = lane >> 4;        // edge group 0..3
    int q = lane & 15;        // dim block: dims [8q, 8q+8)

    int n = cnt[node];
    int off = offs[node];                          // 4-aligned int index
    int srcs = (lane < n) ? csr[off + lane] : 0;   // predicated window preload

    v2f a0 = {0.f, 0.f}, a1 = {0.f, 0.f}, a2 = {0.f, 0.f}, a3 = {0.f, 0.f};

    int nn = n < 64 ? n : 64;
    int t = 0;
    // x4: four line requests issued before any decode
    for (; 4 * t + 16 <= nn; t += 4) {
        int j0 = (t << 2) | g;
        int s0 = __shfl(srcs, j0);
        int s1 = __shfl(srcs, j0 + 4);
        int s2 = __shfl(srcs, j0 + 8);
        int s3 = __shfl(srcs, j0 + 12);
        int2 r0 = *(const int2*)(x8 + ((size_t)s0 << 7) + (q << 3));
        int2 r1 = *(const int2*)(x8 + ((size_t)s1 << 7) + (q << 3));
        int2 r2 = *(const int2*)(x8 + ((size_t)s2 << 7) + (q << 3));
        int2 r3 = *(const int2*)(x8 + ((size_t)s3 << 7) + (q << 3));
        a0 += dec2(r0.x, 0); a1 += dec2(r0.x, 1); a2 += dec2(r0.y, 0); a3 += dec2(r0.y, 1);
        a0 += dec2(r1.x, 0); a1 += dec2(r1.x, 1); a2 += dec2(r1.y, 0); a3 += dec2(r1.y, 1);
        a0 += dec2(r2.x, 0); a1 += dec2(r2.x, 1); a2 += dec2(r2.y, 0); a3 += dec2(r2.y, 1);
        a0 += dec2(r3.x, 0); a1 += dec2(r3.x, 1); a2 += dec2(r3.y, 0); a3 += dec2(r3.y, 1);
    }
    // x2
    for (; 4 * t + 8 <= nn; t += 2) {
        int j0 = (t << 2) | g;
        int s0 = __shfl(srcs, j0);
        int s1 = __shfl(srcs, j0 + 4);
        int2 r0 = *(const int2*)(x8 + ((size_t)s0 << 7) + (q << 3));
        int2 r1 = *(const int2*)(x8 + ((size_t)s1 << 7) + (q << 3));
        a0 += dec2(r0.x, 0); a1 += dec2(r0.x, 1); a2 += dec2(r0.y, 0); a3 += dec2(r0.y, 1);
        a0 += dec2(r1.x, 0); a1 += dec2(r1.x, 1); a2 += dec2(r1.y, 0); a3 += dec2(r1.y, 1);
    }
    // predicated x1 tail
    int T = (nn + 3) >> 2;
    for (; t < T; ++t) {
        int j = (t << 2) | g;
        int s = __shfl(srcs, j);
        if (j < nn) {
            int2 raw = *(const int2*)(x8 + ((size_t)s << 7) + (q << 3));
            a0 += dec2(raw.x, 0); a1 += dec2(raw.x, 1);
            a2 += dec2(raw.y, 0); a3 += dec2(raw.y, 1);
        }
    }
    for (int j = 64 + g; j < n; j += 4) {          // P(deg>64) ~ 1e-20
        int s = csr[off + j];
        int2 raw = *(const int2*)(x8 + ((size_t)s << 7) + (q << 3));
        a0 += dec2(raw.x, 0); a1 += dec2(raw.x, 1);
        a2 += dec2(raw.y, 0); a3 += dec2(raw.y, 1);
    }
    // cross-group reduce (lanes +-16, +-32)
    float av[8] = {a0.x, a0.y, a1.x, a1.y, a2.x, a2.y, a3.x, a3.y};
    #pragma unroll
    for (int k = 0; k < 8; ++k) {
        av[k] += __shfl_xor(av[k], 16);
        av[k] += __shfl_xor(av[k], 32);
    }

    if (g == 0) {
        float fn = (float)n;
        if (MODE == 0) {
            float inv = n > 0 ? 1.0f / fn : 0.0f;
            float m16 = inv * FP8_INV;                       // -> x'_k
            __half2 h16[4];
            #pragma unroll
            for (int k = 0; k < 4; ++k)
                h16[k] = __float22half2_rn(make_float2(av[2 * k] * m16, av[2 * k + 1] * m16));
            __builtin_nontemporal_store(*(v4i*)h16, (v4i*)(x16_out + (size_t)node * DD + q * 8));
            int w0 = enc2(av[0] * inv, av[1] * inv, 0, 0);
            w0 = enc2(av[2] * inv, av[3] * inv, w0, 1);
            int w1 = enc2(av[4] * inv, av[5] * inv, 0, 0);
            w1 = enc2(av[6] * inv, av[7] * inv, w1, 1);
            v2i w01; w01.x = w0; w01.y = w1;
            __builtin_nontemporal_store(w01, (v2i*)(x8_out + ((size_t)node << 7) + (q << 3)));
        } else {
            float rr4 = n > 0 ? 0.25f * sqrtf(fn) : 0.0f;
            float d644 = n > 0 ? 0.25f * FP8_INV * rsqrtf(fn) : 0.0f;
            size_t eo = (size_t)node * DD + q * 8;
            int4 bq = *(const int4*)(embq + eo);
            int4 b1 = *(const int4*)(u1p + eo);
            int4 b2 = *(const int4*)(u2p + eo);
            const __half2* hq = (const __half2*)&bq;
            const __half2* h1 = (const __half2*)&b1;
            const __half2* h2v = (const __half2*)&b2;
            float o8[8];
            #pragma unroll
            for (int k = 0; k < 4; ++k) {
                float2 eq = __half22float2(hq[k]);
                float2 uu1 = __half22float2(h1[k]);
                float2 uu2 = __half22float2(h2v[k]);
                o8[2 * k]     = eq.x + (uu1.x + uu2.x) * rr4 + d644 * av[2 * k];
                o8[2 * k + 1] = eq.y + (uu1.y + uu2.y) * rr4 + d644 * av[2 * k + 1];
            }
            float* dst = out + eo;
            v4f lo; lo.x = o8[0]; lo.y = o8[1]; lo.z = o8[2]; lo.w = o8[3];
            v4f hi; hi.x = o8[4]; hi.y = o8[5]; hi.z = o8[6]; hi.w = o8[7];
            __builtin_nontemporal_store(lo, (v4f*)dst);
            __builtin_nontemporal_store(hi, (v4f*)(dst + 4));
        }
    }
}

// ---------------- launch ----------------

extern "C" void kernel_launch(void* const* d_in, const int* in_sizes, int n_in,
                              void* d_out, int out_size, void* d_ws, size_t ws_size,
                              hipStream_t stream) {
    const float* emb = (const float*)d_in[0];
    const int* ei = (const int*)d_in[1];
    const int E = in_sizes[1] / 2;
    const int* row = ei;        // edge_index[0]
    const int* col = ei + E;    // edge_index[1]
    float* out = (float*)d_out;

    char* w = (char*)d_ws;
    auto align_up = [](size_t v) { return (v + 255) & ~(size_t)255; };
    size_t o = 0;
    int* pcnt = (int*)(w + o);           o = align_up(o + (size_t)NSUB * PCNT_PAD * 4);
    int* cnt  = (int*)(w + o);           o = align_up(o + (size_t)NN * 4);
    int* offs = (int*)(w + o);           o = align_up(o + (size_t)NN * 4);
    int* csr  = (int*)(w + o);           o = align_up(o + (size_t)NSUB * CSTRIDE * 4); // 8.2 MB
    // union: part (7.2 MB, dead after build) shares with xs2_8 (12.8 MB, born in g2)
    char* upx = w + o;                   o = align_up(o + (size_t)NN * DD);            // 12.8 MB
    int* part = (int*)upx;
    unsigned char* xs2_8 = (unsigned char*)upx;
    unsigned char* xs0_8 = (unsigned char*)(w + o); o = align_up(o + (size_t)NN * DD); // 12.8 MB
    unsigned char* xs1_8 = (unsigned char*)(w + o); o = align_up(o + (size_t)NN * DD); // 12.8 MB
    __half* xs1_16 = (__half*)(w + o);   o = align_up(o + (size_t)NN * DD * 2);        // 25.6 MB
    __half* xs2_16 = (__half*)(w + o);   o = align_up(o + (size_t)NN * DD * 2);        // 25.6 MB
    __half* embq   = (__half*)(w + o);   o = align_up(o + (size_t)NN * DD * 2);        // 25.6 MB

    hipMemsetAsync(pcnt, 0, (size_t)NSUB * PCNT_PAD * 4, stream);

    part_kernel<<<(E + PEB - 1) / PEB, 256, 0, stream>>>(row, col, pcnt, part, E);
    build_kernel<<<NSUB, 1024, 0, stream>>>(pcnt, part, cnt, offs, csr);
    conv_kernel<<<(NN * DD / 4 + 255) / 256, 256, 0, stream>>>(emb, cnt, (unsigned int*)xs0_8, embq);

    const int lb = (NN * 64) / 256;  // 25000 blocks, 1 wave per node
    gather_kernel<0><<<lb, 256, 0, stream>>>(xs0_8, cnt, offs, csr, xs1_16, xs1_8,
                                             nullptr, nullptr, nullptr, nullptr);
    gather_kernel<0><<<lb, 256, 0, stream>>>(xs1_8, cnt, offs, csr, xs2_16, xs2_8,
                                             nullptr, nullptr, nullptr, nullptr);
    gather_kernel<1><<<lb, 256, 0, stream>>>(xs2_8, cnt, offs, csr, nullptr, nullptr,
                                             embq, xs1_16, xs2_16, out);
}